// Round 1
// baseline (48.927 us; speedup 1.0000x reference)
//
#include <hip/hip_runtime.h>
#include <math.h>

#define NBLOCKS 2048
#define NTHREADS 256

__global__ __launch_bounds__(NTHREADS) void iou_partial_kernel(
    const float4* __restrict__ a,   // boxes_pred, xywh
    const float4* __restrict__ b,   // boxes, xywh
    float* __restrict__ partials,
    int n)
{
    int tid = blockIdx.x * blockDim.x + threadIdx.x;
    int stride = gridDim.x * blockDim.x;

    float sum = 0.0f;
    for (int i = tid; i < n; i += stride) {
        float4 pa = a[i];
        float4 pb = b[i];

        // xywh -> xyxy (match reference float32 rounding: x2 = x + w)
        float ax2 = pa.x + pa.z;
        float ay2 = pa.y + pa.w;
        float bx2 = pb.x + pb.z;
        float by2 = pb.y + pb.w;

        float ltx = fmaxf(pa.x, pb.x);
        float lty = fmaxf(pa.y, pb.y);
        float rbx = fminf(ax2, bx2);
        float rby = fminf(ay2, by2);

        float wx = fmaxf(rbx - ltx, 0.0f);
        float wy = fmaxf(rby - lty, 0.0f);
        float inter = wx * wy;

        // areas exactly as the reference computes them: (x+w rounded) - x
        float areaA = (ax2 - pa.x) * (ay2 - pa.y);
        float areaB = (bx2 - pb.x) * (by2 - pb.y);

        sum += inter / (areaA + areaB - inter);
    }

    // wave-64 shuffle reduction
    #pragma unroll
    for (int off = 32; off > 0; off >>= 1)
        sum += __shfl_down(sum, off, 64);

    __shared__ float smem[NTHREADS / 64];
    int lane = threadIdx.x & 63;
    int wid  = threadIdx.x >> 6;
    if (lane == 0) smem[wid] = sum;
    __syncthreads();

    if (threadIdx.x == 0) {
        float t = 0.0f;
        #pragma unroll
        for (int w = 0; w < NTHREADS / 64; ++w) t += smem[w];
        partials[blockIdx.x] = t;   // written every call: deterministic
    }
}

__global__ __launch_bounds__(NTHREADS) void iou_final_kernel(
    const float* __restrict__ partials,
    float* __restrict__ out,
    int nblocks,
    int n)
{
    double sum = 0.0;
    for (int i = threadIdx.x; i < nblocks; i += blockDim.x)
        sum += (double)partials[i];

    #pragma unroll
    for (int off = 32; off > 0; off >>= 1)
        sum += __shfl_down(sum, off, 64);

    __shared__ double smem[NTHREADS / 64];
    int lane = threadIdx.x & 63;
    int wid  = threadIdx.x >> 6;
    if (lane == 0) smem[wid] = sum;
    __syncthreads();

    if (threadIdx.x == 0) {
        double t = 0.0;
        #pragma unroll
        for (int w = 0; w < NTHREADS / 64; ++w) t += smem[w];
        double mean = t / (double)n;
        out[0] = (float)(-log(mean));
    }
}

extern "C" void kernel_launch(void* const* d_in, const int* in_sizes, int n_in,
                              void* d_out, int out_size, void* d_ws, size_t ws_size,
                              hipStream_t stream)
{
    const float4* boxes_pred = (const float4*)d_in[0];
    const float4* boxes      = (const float4*)d_in[1];
    float* out = (float*)d_out;
    float* partials = (float*)d_ws;   // NBLOCKS floats = 8 KiB

    int n = in_sizes[0] / 4;          // number of boxes

    iou_partial_kernel<<<NBLOCKS, NTHREADS, 0, stream>>>(boxes_pred, boxes, partials, n);
    iou_final_kernel<<<1, NTHREADS, 0, stream>>>(partials, out, NBLOCKS, n);
}